// Round 10
// baseline (158.236 us; speedup 1.0000x reference)
//
#include <hip/hip_runtime.h>

#define D 512
#define NROWS 8192
#define MROWS 8192
#define NCHUNK 8
#define CHUNK_COLS (MROWS / NCHUNK)   // 1024
#define SWEEPS (CHUNK_COLS / 256)     // 4 sweeps of 256 cols
#define NRB (NROWS / 128)             // 64 row-blocks
#define LOG2E 1.4426950408889634f
#define LN2 0.6931471805599453f

typedef float floatx4 __attribute__((ext_vector_type(4)));
typedef __bf16 bf16x8 __attribute__((ext_vector_type(8)));
typedef unsigned uintx4 __attribute__((ext_vector_type(4)));
typedef int intx8 __attribute__((ext_vector_type(8)));

typedef __attribute__((address_space(1))) void* as1_void_p;
typedef __attribute__((address_space(3))) void* as3_void_p;

__device__ __forceinline__ void async_cp16(const void* g, void* l) {
    __builtin_amdgcn_global_load_lds((as1_void_p)(void*)g, (as3_void_p)l, 16, 0, 0);
}

__device__ __forceinline__ unsigned short f2bf(float f) {
    unsigned u = __float_as_uint(f);
    u += 0x7fffu + ((u >> 16) & 1u);
    return (unsigned short)(u >> 16);
}

__device__ __forceinline__ float fast_tanh(float x) {
    const float xc = fminf(fmaxf(x, -15.0f), 15.0f);
    const float e = __builtin_exp2f(xc * (2.0f * LOG2E));
    return (e - 1.0f) * __builtin_amdgcn_rcpf(e + 1.0f);
}

__device__ __forceinline__ unsigned pack2(float a, float b) {
    return (unsigned)f2bf(a) | ((unsigned)f2bf(b) << 16);
}

// build a bf16x8 fragment (RNE) from two LDS float4s
__device__ __forceinline__ bf16x8 cvt8(const float4 lo, const float4 hi) {
    uintx4 u;
    u.x = pack2(lo.x, lo.y); u.y = pack2(lo.z, lo.w);
    u.z = pack2(hi.x, hi.y); u.w = pack2(hi.z, hi.w);
    return *(bf16x8*)&u;
}

// ---------------------------------------------------------------------------
// Kernel 1: blocks [0,512): f = tanh(mu @ W^T + b) -> fp8 + ||f~||^2 atomics.
//   mu/W staged as RAW FP32 via global_load_lds; converted to bf16 at
//   fragment-build (RNE -> bit-identical to the old pre-conversion pass).
//   128x64 tiles, BK=32 floats (128 B/row), granule-XOR f(row)=row&7.
// blocks [512, 2560): x-prep -> xb8 = fp8(x*log2e), xsq = sum of quantized^2.
#define FGB 512
#define XBLK (NROWS / 4)            // 2048
__global__ __launch_bounds__(256, 2)
void k_fgemm_xprep(const float* __restrict__ mu,
                   const float* __restrict__ W,
                   const float* __restrict__ bias,
                   const float* __restrict__ x,
                   unsigned char* __restrict__ fb8,
                   unsigned char* __restrict__ xb8,
                   float* __restrict__ fsq,
                   float* __restrict__ xsq) {
    const int bid = blockIdx.x;
    const int tid = threadIdx.x;

    if (bid >= FGB) {
        // ---- x-prep: 4 rows per block, one wave per row
        const int row = (bid - FGB) * 4 + (tid >> 6);
        const int lane = tid & 63;
        const float4 v0 = ((const float4*)(x + (size_t)row * D))[lane * 2];
        const float4 v1 = ((const float4*)(x + (size_t)row * D))[lane * 2 + 1];
        int p0 = 0, p1 = 0;
        p0 = __builtin_amdgcn_cvt_pk_fp8_f32(v0.x * LOG2E, v0.y * LOG2E, p0, false);
        p0 = __builtin_amdgcn_cvt_pk_fp8_f32(v0.z * LOG2E, v0.w * LOG2E, p0, true);
        p1 = __builtin_amdgcn_cvt_pk_fp8_f32(v1.x * LOG2E, v1.y * LOG2E, p1, false);
        p1 = __builtin_amdgcn_cvt_pk_fp8_f32(v1.z * LOG2E, v1.w * LOG2E, p1, true);
        uint2 o; o.x = (unsigned)p0; o.y = (unsigned)p1;
        ((uint2*)(xb8 + (size_t)row * D))[lane] = o;
        float q, s = 0.f;
        q = __builtin_amdgcn_cvt_f32_fp8(p0, 0); s += q * q;
        q = __builtin_amdgcn_cvt_f32_fp8(p0, 1); s += q * q;
        q = __builtin_amdgcn_cvt_f32_fp8(p0, 2); s += q * q;
        q = __builtin_amdgcn_cvt_f32_fp8(p0, 3); s += q * q;
        q = __builtin_amdgcn_cvt_f32_fp8(p1, 0); s += q * q;
        q = __builtin_amdgcn_cvt_f32_fp8(p1, 1); s += q * q;
        q = __builtin_amdgcn_cvt_f32_fp8(p1, 2); s += q * q;
        q = __builtin_amdgcn_cvt_f32_fp8(p1, 3); s += q * q;
        #pragma unroll
        for (int m = 1; m < 64; m <<= 1) s += __shfl_xor(s, m);
        if (lane == 0) xsq[row] = s;
        return;
    }

    // ---- fgemm tile (fp32 staging)
    __shared__ char Afp[128 * 128];   // 16 KB: 128 rows x 32 fp32
    __shared__ char Bfp[64 * 128];    // 8 KB:  64 rows x 32 fp32

    const int wave = tid >> 6;
    const int lane = tid & 63;
    const int wr = wave >> 1, wc = wave & 1;
    const int g = lane >> 4;
    const int lm = lane & 15;

    const int row0 = (bid & 63) * 128;
    const int col0 = (bid >> 6) * 64;

    // staging: granule-XOR srcg = (lane&7) ^ (row&7); row&7 == lane>>3 here.
    const int srcg = (lane & 7) ^ (lane >> 3);
    const char* pA[4];
    char* dA[4];
    #pragma unroll
    for (int p = 0; p < 4; ++p) {
        const int row = 32 * wave + 8 * p + (lane >> 3);
        pA[p] = (const char*)(mu + (size_t)(row0 + row) * D) + srcg * 16;
        dA[p] = Afp + wave * 4096 + p * 1024 + lane * 16;
    }
    const char* pB[2];
    char* dB[2];
    #pragma unroll
    for (int p = 0; p < 2; ++p) {
        const int row = 16 * wave + 8 * p + (lane >> 3);
        pB[p] = (const char*)(W + (size_t)(col0 + row) * D) + srcg * 16;
        dB[p] = Bfp + wave * 2048 + p * 1024 + lane * 16;
    }

    const int f8 = lm & 7;
    const int q0 = ((2 * g) ^ f8) * 16;
    const char* fragA = Afp + (64 * wr + lm) * 128;
    const char* fragB = Bfp + (32 * wc + lm) * 128;

    floatx4 acc[4][2];
    const floatx4 zz = {0.f, 0.f, 0.f, 0.f};
    #pragma unroll
    for (int i = 0; i < 4; ++i)
        #pragma unroll
        for (int j = 0; j < 2; ++j) acc[i][j] = zz;

    for (int kt = 0; kt < 16; ++kt) {
        const int k0 = kt * 128;   // bytes: 32 floats
        #pragma unroll
        for (int p = 0; p < 4; ++p) async_cp16(pA[p] + k0, dA[p]);
        #pragma unroll
        for (int p = 0; p < 2; ++p) async_cp16(pB[p] + k0, dB[p]);
        __syncthreads();
        bf16x8 af[4], bfr[2];
        #pragma unroll
        for (int i = 0; i < 4; ++i) {
            const char* pa = fragA + i * 2048;
            af[i] = cvt8(*(const float4*)(pa + q0), *(const float4*)(pa + (q0 ^ 16)));
        }
        #pragma unroll
        for (int j = 0; j < 2; ++j) {
            const char* pb = fragB + j * 2048;
            bfr[j] = cvt8(*(const float4*)(pb + q0), *(const float4*)(pb + (q0 ^ 16)));
        }
        #pragma unroll
        for (int i = 0; i < 4; ++i)
            #pragma unroll
            for (int j = 0; j < 2; ++j)
                acc[i][j] = __builtin_amdgcn_mfma_f32_16x16x32_bf16(af[i], bfr[j], acc[i][j], 0, 0, 0);
        __syncthreads();
    }

    float bcol[2];
    #pragma unroll
    for (int j = 0; j < 2; ++j) bcol[j] = bias[col0 + 32 * wc + 16 * j + lm];
    #pragma unroll
    for (int i = 0; i < 4; ++i) {
        #pragma unroll
        for (int r = 0; r < 4; ++r) {
            const int row = row0 + 64 * wr + 16 * i + 4 * g + r;
            float sq = 0.f;
            #pragma unroll
            for (int j = 0; j < 2; ++j) {
                const int col = col0 + 32 * wc + 16 * j + lm;
                const float tv = fast_tanh(acc[i][j][r] + bcol[j]);
                const int pk = __builtin_amdgcn_cvt_pk_fp8_f32(tv, tv, 0, false);
                fb8[(size_t)row * D + col] = (unsigned char)(pk & 0xff);
                const float qf = __builtin_amdgcn_cvt_f32_fp8(pk, 0);
                sq += qf * qf;
            }
            #pragma unroll
            for (int d = 1; d < 16; d <<= 1) sq += __shfl_xor(sq, d);
            if (lm == 0) atomicAdd(fsq + row, sq);
        }
    }
}

// ---------------------------------------------------------------------------
// Kernel 2: MX-scaled fp8 cross-GEMM (K=128, unit scales) + per-lane online
// logsumexp. 128 rows x 256 cols per sweep; BK=128 B per barrier pair.
// Granule-XOR f(row)=row&7: 8-lane b128 phases hit 8 distinct granules
// (conflict-free; R9's (row>>1)&7 paired lanes -> 2-way, 3.1M conflicts).
__global__ __launch_bounds__(256, 2)
void k_cross(const unsigned char* __restrict__ xb8,
             const unsigned char* __restrict__ fb8,
             const float* __restrict__ fsq,
             float* __restrict__ pmax,
             float* __restrict__ psum) {
    __shared__ char Ab[128 * 128];   // 16 KB
    __shared__ char Bb[256 * 128];   // 32 KB
    __shared__ float mbuf[128], sbuf[128];

    const int tid = threadIdx.x;
    const int wave = tid >> 6;
    const int lane = tid & 63;
    const int wr = wave >> 1, wc = wave & 1;
    const int g = lane >> 4;
    const int lm = lane & 15;

    const int row0 = blockIdx.x * 128;
    const int chunk = blockIdx.y;

    const int srcg = (lane & 7) ^ (lane >> 3);   // f(row)=row&7; row&7==lane>>3
    const unsigned char* pA[4];
    char* dA[4];
    size_t offB[8];
    char* dB[8];
    #pragma unroll
    for (int p = 0; p < 4; ++p) {
        const int row = 32 * wave + 8 * p + (lane >> 3);
        pA[p] = xb8 + (size_t)(row0 + row) * D + srcg * 16;
        dA[p] = Ab + wave * 4096 + p * 1024 + lane * 16;
    }
    #pragma unroll
    for (int p = 0; p < 8; ++p) {
        const int row = 64 * wave + 8 * p + (lane >> 3);
        offB[p] = (size_t)row * D + srcg * 16;
        dB[p] = Bb + wave * 8192 + p * 1024 + lane * 16;
    }

    const int f8 = lm & 7;
    const int pg0 = ((2 * g) ^ f8) * 16;
    const char* fragA = Ab + (64 * wr + lm) * 128;
    const char* fragB = Bb + (128 * wc + lm) * 128;

    float m_loc[4][4], s_loc[4][4];
    #pragma unroll
    for (int i = 0; i < 4; ++i)
        #pragma unroll
        for (int r = 0; r < 4; ++r) { m_loc[i][r] = -__builtin_inff(); s_loc[i][r] = 0.f; }

    for (int st = 0; st < SWEEPS; ++st) {
        const int col0 = chunk * CHUNK_COLS + st * 256;
        const unsigned char* gBbase = fb8 + (size_t)col0 * D;

        floatx4 acc[4][8];
        const floatx4 zz = {0.f, 0.f, 0.f, 0.f};
        #pragma unroll
        for (int i = 0; i < 4; ++i)
            #pragma unroll
            for (int j = 0; j < 8; ++j) acc[i][j] = zz;

        for (int kt = 0; kt < 4; ++kt) {
            const int k0 = kt * 128;
            #pragma unroll
            for (int p = 0; p < 4; ++p) async_cp16(pA[p] + k0, dA[p]);
            #pragma unroll
            for (int p = 0; p < 8; ++p) async_cp16(gBbase + offB[p] + k0, dB[p]);
            __syncthreads();

            intx8 av[4];
            #pragma unroll
            for (int i = 0; i < 4; ++i) {
                const char* pa = fragA + i * 2048;
                const int4 lo = *(const int4*)(pa + pg0);
                const int4 hi = *(const int4*)(pa + (pg0 ^ 16));
                av[i] = (intx8){lo.x, lo.y, lo.z, lo.w, hi.x, hi.y, hi.z, hi.w};
            }
            #pragma unroll
            for (int j = 0; j < 8; ++j) {
                const char* pb = fragB + j * 2048;
                const int4 lo = *(const int4*)(pb + pg0);
                const int4 hi = *(const int4*)(pb + (pg0 ^ 16));
                const intx8 bv = {lo.x, lo.y, lo.z, lo.w, hi.x, hi.y, hi.z, hi.w};
                acc[0][j] = __builtin_amdgcn_mfma_scale_f32_16x16x128_f8f6f4(
                    av[0], bv, acc[0][j], 0, 0, 0, 0x7f7f7f7f, 0, 0x7f7f7f7f);
                acc[1][j] = __builtin_amdgcn_mfma_scale_f32_16x16x128_f8f6f4(
                    av[1], bv, acc[1][j], 0, 0, 0, 0x7f7f7f7f, 0, 0x7f7f7f7f);
                acc[2][j] = __builtin_amdgcn_mfma_scale_f32_16x16x128_f8f6f4(
                    av[2], bv, acc[2][j], 0, 0, 0, 0x7f7f7f7f, 0, 0x7f7f7f7f);
                acc[3][j] = __builtin_amdgcn_mfma_scale_f32_16x16x128_f8f6f4(
                    av[3], bv, acc[3][j], 0, 0, 0, 0x7f7f7f7f, 0, 0x7f7f7f7f);
            }
            __syncthreads();
        }

        float hf[8];
        #pragma unroll
        for (int j = 0; j < 8; ++j)
            hf[j] = 0.5f * LOG2E * fsq[col0 + 128 * wc + 16 * j + lm];
        #pragma unroll
        for (int i = 0; i < 4; ++i) {
            #pragma unroll
            for (int r = 0; r < 4; ++r) {
                float v[8];
                float mm = -__builtin_inff();
                #pragma unroll
                for (int j = 0; j < 8; ++j) {
                    v[j] = acc[i][j][r] - hf[j];
                    mm = fmaxf(mm, v[j]);
                }
                const float nm = fmaxf(m_loc[i][r], mm);
                float s = s_loc[i][r] * __builtin_exp2f(m_loc[i][r] - nm);
                #pragma unroll
                for (int j = 0; j < 8; ++j) s += __builtin_exp2f(v[j] - nm);
                s_loc[i][r] = s;
                m_loc[i][r] = nm;
            }
        }
    }

    // merge across 16-lane group
    #pragma unroll
    for (int i = 0; i < 4; ++i) {
        #pragma unroll
        for (int r = 0; r < 4; ++r) {
            float m = m_loc[i][r], s = s_loc[i][r];
            #pragma unroll
            for (int d = 1; d < 16; d <<= 1) {
                const float om = __shfl_xor(m, d);
                const float os = __shfl_xor(s, d);
                const float nm = fmaxf(m, om);
                s = s * __builtin_exp2f(m - nm) + os * __builtin_exp2f(om - nm);
                m = nm;
            }
            m_loc[i][r] = m; s_loc[i][r] = s;
        }
    }
    // merge the two column-waves via LDS, write partials
    if (wc == 0 && lm == 0) {
        #pragma unroll
        for (int i = 0; i < 4; ++i)
            #pragma unroll
            for (int r = 0; r < 4; ++r) {
                const int rl = 64 * wr + 16 * i + 4 * g + r;
                mbuf[rl] = m_loc[i][r]; sbuf[rl] = s_loc[i][r];
            }
    }
    __syncthreads();
    if (wc == 1 && lm == 0) {
        #pragma unroll
        for (int i = 0; i < 4; ++i)
            #pragma unroll
            for (int r = 0; r < 4; ++r) {
                const int rl = 64 * wr + 16 * i + 4 * g + r;
                const float om = mbuf[rl], os = sbuf[rl];
                float m = m_loc[i][r], s = s_loc[i][r];
                const float nm = fmaxf(m, om);
                s = s * __builtin_exp2f(m - nm) + os * __builtin_exp2f(om - nm);
                pmax[(size_t)(row0 + rl) * NCHUNK + chunk] = nm;
                psum[(size_t)(row0 + rl) * NCHUNK + chunk] = s;
            }
    }
}

// ---------------------------------------------------------------------------
// Kernel 3: combine partials -> out += -sum lse.
// lse_nats = LN2*(gm + log2 s) - 0.5*LN2^2*X2   (X2 = sum q^2, q = log2e*x~)
__global__ void k_finish(const float* __restrict__ pmax,
                         const float* __restrict__ psum,
                         const float* __restrict__ xsq,
                         float* __restrict__ out) {
    const int row = blockIdx.x * 256 + threadIdx.x;
    const float4* pm4 = (const float4*)(pmax + (size_t)row * NCHUNK);
    const float4* ps4 = (const float4*)(psum + (size_t)row * NCHUNK);
    float pm[NCHUNK], ps[NCHUNK];
    #pragma unroll
    for (int c = 0; c < NCHUNK / 4; ++c) {
        const float4 a = pm4[c], b = ps4[c];
        pm[4*c] = a.x; pm[4*c+1] = a.y; pm[4*c+2] = a.z; pm[4*c+3] = a.w;
        ps[4*c] = b.x; ps[4*c+1] = b.y; ps[4*c+2] = b.z; ps[4*c+3] = b.w;
    }
    float gm = -__builtin_inff();
    #pragma unroll
    for (int c = 0; c < NCHUNK; ++c) gm = fmaxf(gm, pm[c]);
    float s = 0.f;
    #pragma unroll
    for (int c = 0; c < NCHUNK; ++c) s += ps[c] * __builtin_exp2f(pm[c] - gm);
    float lse = LN2 * (gm + __builtin_log2f(s)) - 0.5f * (LN2 * LN2) * xsq[row];
    #pragma unroll
    for (int m = 1; m < 64; m <<= 1) lse += __shfl_xor(lse, m);
    __shared__ float ws4[4];
    if ((threadIdx.x & 63) == 0) ws4[threadIdx.x >> 6] = lse;
    __syncthreads();
    if (threadIdx.x == 0) atomicAdd(out, -(ws4[0] + ws4[1] + ws4[2] + ws4[3]));
}

// ---------------------------------------------------------------------------
extern "C" void kernel_launch(void* const* d_in, const int* in_sizes, int n_in,
                              void* d_out, int out_size, void* d_ws, size_t ws_size,
                              hipStream_t stream) {
    const float* x  = (const float*)d_in[0];   // (8192, 512)
    const float* mu = (const float*)d_in[1];   // (8192, 512)
    const float* W  = (const float*)d_in[2];   // (512, 512)
    const float* b  = (const float*)d_in[3];   // (512,)

    char* ws = (char*)d_ws;
    unsigned char* xb8 = (unsigned char*)(ws);                      // 4 MB
    unsigned char* fb8 = (unsigned char*)(ws + (4u << 20));         // 4 MB
    float* xsq  = (float*)(ws + (8u << 20));                        // 32 KB
    float* fsq  = xsq + NROWS;                                      // 32 KB
    float* pmax = fsq + MROWS;                                      // 256 KB
    float* psum = pmax + (size_t)NROWS * NCHUNK;                    // 256 KB

    float* out = (float*)d_out;

    hipMemsetAsync(fsq, 0, MROWS * sizeof(float), stream);
    hipMemsetAsync(out, 0, sizeof(float), stream);
    hipLaunchKernelGGL(k_fgemm_xprep, dim3(FGB + XBLK), dim3(256), 0, stream,
                       mu, W, b, x, fb8, xb8, fsq, xsq);
    hipLaunchKernelGGL(k_cross, dim3(NRB, NCHUNK), dim3(256), 0, stream,
                       xb8, fb8, fsq, pmax, psum);
    hipLaunchKernelGGL(k_finish, dim3(NROWS / 256), dim3(256), 0, stream,
                       pmax, psum, xsq, out);
}

// Round 11
// 146.770 us; speedup vs baseline: 1.0781x; 1.0781x over previous
//
#include <hip/hip_runtime.h>

#define D 512
#define NROWS 8192
#define MROWS 8192
#define NCHUNK 8
#define CHUNK_COLS (MROWS / NCHUNK)   // 1024
#define SWEEPS (CHUNK_COLS / 256)     // 4 sweeps of 256 cols
#define NRB (NROWS / 128)             // 64 row-blocks
#define LOG2E 1.4426950408889634f
#define LN2 0.6931471805599453f

typedef float floatx4 __attribute__((ext_vector_type(4)));
typedef __bf16 bf16x8 __attribute__((ext_vector_type(8)));
typedef unsigned uintx4 __attribute__((ext_vector_type(4)));
typedef int intx8 __attribute__((ext_vector_type(8)));

typedef __attribute__((address_space(1))) void* as1_void_p;
typedef __attribute__((address_space(3))) void* as3_void_p;

__device__ __forceinline__ void async_cp16(const void* g, void* l) {
    __builtin_amdgcn_global_load_lds((as1_void_p)(void*)g, (as3_void_p)l, 16, 0, 0);
}

__device__ __forceinline__ unsigned short f2bf(float f) {
    unsigned u = __float_as_uint(f);
    u += 0x7fffu + ((u >> 16) & 1u);
    return (unsigned short)(u >> 16);
}

__device__ __forceinline__ float fast_tanh(float x) {
    const float xc = fminf(fmaxf(x, -15.0f), 15.0f);
    const float e = __builtin_exp2f(xc * (2.0f * LOG2E));
    return (e - 1.0f) * __builtin_amdgcn_rcpf(e + 1.0f);
}

__device__ __forceinline__ unsigned pack2(float a, float b) {
    return (unsigned)f2bf(a) | ((unsigned)f2bf(b) << 16);
}

// ---------------------------------------------------------------------------
// Kernel 1: mu -> bf16 (2048 blocks), W -> bf16 + zero fsq/out (128 blocks).
#define MUBLK (MROWS * D / 2048)    // 2048
#define WBLK (D * D / 2048)         // 128
__global__ void k_convmw(const float* __restrict__ mu,
                         const float* __restrict__ W,
                         unsigned short* __restrict__ mub,
                         unsigned short* __restrict__ Wb,
                         float* __restrict__ fsq,
                         float* __restrict__ out) {
    const int bid = blockIdx.x;
    const int t = threadIdx.x;  // 256
    if (bid < MUBLK) {
        const size_t i = ((size_t)bid * 256 + t) * 2;
        const float4 v0 = ((const float4*)mu)[i];
        const float4 v1 = ((const float4*)mu)[i + 1];
        uintx4 o;
        o.x = pack2(v0.x, v0.y); o.y = pack2(v0.z, v0.w);
        o.z = pack2(v1.x, v1.y); o.w = pack2(v1.z, v1.w);
        ((uintx4*)mub)[i / 2] = o;
    } else {
        const int wb = bid - MUBLK;
        if (wb == 0 && t == 0) out[0] = 0.f;
        const size_t i = ((size_t)wb * 256 + t) * 2;
        const float4 v0 = ((const float4*)W)[i];
        const float4 v1 = ((const float4*)W)[i + 1];
        uintx4 o;
        o.x = pack2(v0.x, v0.y); o.y = pack2(v0.z, v0.w);
        o.z = pack2(v1.x, v1.y); o.w = pack2(v1.z, v1.w);
        ((uintx4*)Wb)[i / 2] = o;
        if (t < 64) fsq[wb * 64 + t] = 0.f;
    }
}

// ---------------------------------------------------------------------------
// Kernel 2: blocks [0,512): f = tanh(mu @ W^T + b) -> fp8 + ||f~||^2 atomics
//   (128x64 tiles, bf16 staging, BK=64: two 32-k halves per barrier pair).
// blocks [512, 2560): x-prep -> xb8 = fp8(x*log2e), xsq = sum of quantized^2.
#define FGB 512
#define XBLK (NROWS / 4)            // 2048
__global__ __launch_bounds__(256, 2)
void k_fgemm_xprep(const unsigned short* __restrict__ mub,
                   const unsigned short* __restrict__ Wb,
                   const float* __restrict__ bias,
                   const float* __restrict__ x,
                   unsigned char* __restrict__ fb8,
                   unsigned char* __restrict__ xb8,
                   float* __restrict__ fsq,
                   float* __restrict__ xsq) {
    const int bid = blockIdx.x;
    const int tid = threadIdx.x;

    if (bid >= FGB) {
        // ---- x-prep: 4 rows per block, one wave per row
        const int row = (bid - FGB) * 4 + (tid >> 6);
        const int lane = tid & 63;
        const float4 v0 = ((const float4*)(x + (size_t)row * D))[lane * 2];
        const float4 v1 = ((const float4*)(x + (size_t)row * D))[lane * 2 + 1];
        int p0 = 0, p1 = 0;
        p0 = __builtin_amdgcn_cvt_pk_fp8_f32(v0.x * LOG2E, v0.y * LOG2E, p0, false);
        p0 = __builtin_amdgcn_cvt_pk_fp8_f32(v0.z * LOG2E, v0.w * LOG2E, p0, true);
        p1 = __builtin_amdgcn_cvt_pk_fp8_f32(v1.x * LOG2E, v1.y * LOG2E, p1, false);
        p1 = __builtin_amdgcn_cvt_pk_fp8_f32(v1.z * LOG2E, v1.w * LOG2E, p1, true);
        uint2 o; o.x = (unsigned)p0; o.y = (unsigned)p1;
        ((uint2*)(xb8 + (size_t)row * D))[lane] = o;
        float q, s = 0.f;
        q = __builtin_amdgcn_cvt_f32_fp8(p0, 0); s += q * q;
        q = __builtin_amdgcn_cvt_f32_fp8(p0, 1); s += q * q;
        q = __builtin_amdgcn_cvt_f32_fp8(p0, 2); s += q * q;
        q = __builtin_amdgcn_cvt_f32_fp8(p0, 3); s += q * q;
        q = __builtin_amdgcn_cvt_f32_fp8(p1, 0); s += q * q;
        q = __builtin_amdgcn_cvt_f32_fp8(p1, 1); s += q * q;
        q = __builtin_amdgcn_cvt_f32_fp8(p1, 2); s += q * q;
        q = __builtin_amdgcn_cvt_f32_fp8(p1, 3); s += q * q;
        #pragma unroll
        for (int m = 1; m < 64; m <<= 1) s += __shfl_xor(s, m);
        if (lane == 0) xsq[row] = s;
        return;
    }

    // ---- fgemm tile (bf16 staging, BK=64)
    __shared__ unsigned short Ab[2][128 * 32];   // 16 KB
    __shared__ unsigned short Bb[2][64 * 32];    // 8 KB

    const int wave = tid >> 6;
    const int lane = tid & 63;
    const int wr = wave >> 1, wc = wave & 1;
    const int g = lane >> 4;
    const int lm = lane & 15;

    const int row0 = (bid & 63) * 128;
    const int col0 = (bid >> 6) * 64;

    const int srow = tid >> 2;
    const int gsrc = (tid & 3) ^ ((srow >> 1) & 3);
    const unsigned short* gA = mub + (size_t)(row0 + srow) * D + gsrc * 8;
    const unsigned short* gB = Wb  + (size_t)(col0 + srow) * D + gsrc * 8;
    char* lA0 = ((char*)Ab[0]) + wave * 1024;
    char* lA1 = ((char*)Ab[1]) + wave * 1024;
    char* lB0 = ((char*)Bb[0]) + wave * 1024;
    char* lB1 = ((char*)Bb[1]) + wave * 1024;

    const int xsel = (lm >> 1) & 3;
    const unsigned short* fragA0 = Ab[0] + (64 * wr + lm) * 32 + (g ^ xsel) * 8;
    const unsigned short* fragB0 = Bb[0] + (32 * wc + lm) * 32 + (g ^ xsel) * 8;

    floatx4 acc[4][2];
    const floatx4 zz = {0.f, 0.f, 0.f, 0.f};
    #pragma unroll
    for (int i = 0; i < 4; ++i)
        #pragma unroll
        for (int j = 0; j < 2; ++j) acc[i][j] = zz;

    for (int kt = 0; kt < 8; ++kt) {
        const int k0 = kt * 64;
        async_cp16(gA + k0, lA0);
        async_cp16(gA + 64 * D + k0, lA0 + 4096);
        async_cp16(gB + k0, lB0);
        async_cp16(gA + k0 + 32, lA1);
        async_cp16(gA + 64 * D + k0 + 32, lA1 + 4096);
        async_cp16(gB + k0 + 32, lB1);
        __syncthreads();
        #pragma unroll
        for (int h = 0; h < 2; ++h) {
            const unsigned short* fA = fragA0 + h * 4096;   // Ab[h]
            const unsigned short* fB = fragB0 + h * 2048;   // Bb[h]
            bf16x8 af[4], bfr[2];
            #pragma unroll
            for (int i = 0; i < 4; ++i) af[i] = *(const bf16x8*)(fA + i * 512);
            #pragma unroll
            for (int j = 0; j < 2; ++j) bfr[j] = *(const bf16x8*)(fB + j * 512);
            #pragma unroll
            for (int i = 0; i < 4; ++i)
                #pragma unroll
                for (int j = 0; j < 2; ++j)
                    acc[i][j] = __builtin_amdgcn_mfma_f32_16x16x32_bf16(af[i], bfr[j], acc[i][j], 0, 0, 0);
        }
        __syncthreads();
    }

    float bcol[2];
    #pragma unroll
    for (int j = 0; j < 2; ++j) bcol[j] = bias[col0 + 32 * wc + 16 * j + lm];
    #pragma unroll
    for (int i = 0; i < 4; ++i) {
        #pragma unroll
        for (int r = 0; r < 4; ++r) {
            const int row = row0 + 64 * wr + 16 * i + 4 * g + r;
            float sq = 0.f;
            #pragma unroll
            for (int j = 0; j < 2; ++j) {
                const int col = col0 + 32 * wc + 16 * j + lm;
                const float tv = fast_tanh(acc[i][j][r] + bcol[j]);
                const int pk = __builtin_amdgcn_cvt_pk_fp8_f32(tv, tv, 0, false);
                fb8[(size_t)row * D + col] = (unsigned char)(pk & 0xff);
                const float qf = __builtin_amdgcn_cvt_f32_fp8(pk, 0);
                sq += qf * qf;
            }
            #pragma unroll
            for (int d = 1; d < 16; d <<= 1) sq += __shfl_xor(sq, d);
            if (lm == 0) atomicAdd(fsq + row, sq);
        }
    }
}

// ---------------------------------------------------------------------------
// Kernel 3: MX-scaled fp8 cross-GEMM (K=128, unit scales) + per-lane online
// logsumexp. Byte-identical to R10's k_cross (61.7 us best-known).
// Note: SQ_LDS_BANK_CONFLICT ~3.1M here = 4/b128-read structural (2-way
// aliasing, free per m136) — not actionable.
__global__ __launch_bounds__(256, 2)
void k_cross(const unsigned char* __restrict__ xb8,
             const unsigned char* __restrict__ fb8,
             const float* __restrict__ fsq,
             float* __restrict__ pmax,
             float* __restrict__ psum) {
    __shared__ char Ab[128 * 128];   // 16 KB
    __shared__ char Bb[256 * 128];   // 32 KB
    __shared__ float mbuf[128], sbuf[128];

    const int tid = threadIdx.x;
    const int wave = tid >> 6;
    const int lane = tid & 63;
    const int wr = wave >> 1, wc = wave & 1;
    const int g = lane >> 4;
    const int lm = lane & 15;

    const int row0 = blockIdx.x * 128;
    const int chunk = blockIdx.y;

    const int srcg = (lane & 7) ^ (lane >> 3);
    const unsigned char* pA[4];
    char* dA[4];
    size_t offB[8];
    char* dB[8];
    #pragma unroll
    for (int p = 0; p < 4; ++p) {
        const int row = 32 * wave + 8 * p + (lane >> 3);
        pA[p] = xb8 + (size_t)(row0 + row) * D + srcg * 16;
        dA[p] = Ab + wave * 4096 + p * 1024 + lane * 16;
    }
    #pragma unroll
    for (int p = 0; p < 8; ++p) {
        const int row = 64 * wave + 8 * p + (lane >> 3);
        offB[p] = (size_t)row * D + srcg * 16;
        dB[p] = Bb + wave * 8192 + p * 1024 + lane * 16;
    }

    const int f8 = lm & 7;
    const int pg0 = ((2 * g) ^ f8) * 16;
    const char* fragA = Ab + (64 * wr + lm) * 128;
    const char* fragB = Bb + (128 * wc + lm) * 128;

    float m_loc[4][4], s_loc[4][4];
    #pragma unroll
    for (int i = 0; i < 4; ++i)
        #pragma unroll
        for (int r = 0; r < 4; ++r) { m_loc[i][r] = -__builtin_inff(); s_loc[i][r] = 0.f; }

    for (int st = 0; st < SWEEPS; ++st) {
        const int col0 = chunk * CHUNK_COLS + st * 256;
        const unsigned char* gBbase = fb8 + (size_t)col0 * D;

        floatx4 acc[4][8];
        const floatx4 zz = {0.f, 0.f, 0.f, 0.f};
        #pragma unroll
        for (int i = 0; i < 4; ++i)
            #pragma unroll
            for (int j = 0; j < 8; ++j) acc[i][j] = zz;

        for (int kt = 0; kt < 4; ++kt) {
            const int k0 = kt * 128;
            #pragma unroll
            for (int p = 0; p < 4; ++p) async_cp16(pA[p] + k0, dA[p]);
            #pragma unroll
            for (int p = 0; p < 8; ++p) async_cp16(gBbase + offB[p] + k0, dB[p]);
            __syncthreads();

            intx8 av[4];
            #pragma unroll
            for (int i = 0; i < 4; ++i) {
                const char* pa = fragA + i * 2048;
                const int4 lo = *(const int4*)(pa + pg0);
                const int4 hi = *(const int4*)(pa + (pg0 ^ 16));
                av[i] = (intx8){lo.x, lo.y, lo.z, lo.w, hi.x, hi.y, hi.z, hi.w};
            }
            #pragma unroll
            for (int j = 0; j < 8; ++j) {
                const char* pb = fragB + j * 2048;
                const int4 lo = *(const int4*)(pb + pg0);
                const int4 hi = *(const int4*)(pb + (pg0 ^ 16));
                const intx8 bv = {lo.x, lo.y, lo.z, lo.w, hi.x, hi.y, hi.z, hi.w};
                acc[0][j] = __builtin_amdgcn_mfma_scale_f32_16x16x128_f8f6f4(
                    av[0], bv, acc[0][j], 0, 0, 0, 0x7f7f7f7f, 0, 0x7f7f7f7f);
                acc[1][j] = __builtin_amdgcn_mfma_scale_f32_16x16x128_f8f6f4(
                    av[1], bv, acc[1][j], 0, 0, 0, 0x7f7f7f7f, 0, 0x7f7f7f7f);
                acc[2][j] = __builtin_amdgcn_mfma_scale_f32_16x16x128_f8f6f4(
                    av[2], bv, acc[2][j], 0, 0, 0, 0x7f7f7f7f, 0, 0x7f7f7f7f);
                acc[3][j] = __builtin_amdgcn_mfma_scale_f32_16x16x128_f8f6f4(
                    av[3], bv, acc[3][j], 0, 0, 0, 0x7f7f7f7f, 0, 0x7f7f7f7f);
            }
            __syncthreads();
        }

        float hf[8];
        #pragma unroll
        for (int j = 0; j < 8; ++j)
            hf[j] = 0.5f * LOG2E * fsq[col0 + 128 * wc + 16 * j + lm];
        #pragma unroll
        for (int i = 0; i < 4; ++i) {
            #pragma unroll
            for (int r = 0; r < 4; ++r) {
                float v[8];
                float mm = -__builtin_inff();
                #pragma unroll
                for (int j = 0; j < 8; ++j) {
                    v[j] = acc[i][j][r] - hf[j];
                    mm = fmaxf(mm, v[j]);
                }
                const float nm = fmaxf(m_loc[i][r], mm);
                float s = s_loc[i][r] * __builtin_exp2f(m_loc[i][r] - nm);
                #pragma unroll
                for (int j = 0; j < 8; ++j) s += __builtin_exp2f(v[j] - nm);
                s_loc[i][r] = s;
                m_loc[i][r] = nm;
            }
        }
    }

    // merge across 16-lane group
    #pragma unroll
    for (int i = 0; i < 4; ++i) {
        #pragma unroll
        for (int r = 0; r < 4; ++r) {
            float m = m_loc[i][r], s = s_loc[i][r];
            #pragma unroll
            for (int d = 1; d < 16; d <<= 1) {
                const float om = __shfl_xor(m, d);
                const float os = __shfl_xor(s, d);
                const float nm = fmaxf(m, om);
                s = s * __builtin_exp2f(m - nm) + os * __builtin_exp2f(om - nm);
                m = nm;
            }
            m_loc[i][r] = m; s_loc[i][r] = s;
        }
    }
    // merge the two column-waves via LDS, write partials
    if (wc == 0 && lm == 0) {
        #pragma unroll
        for (int i = 0; i < 4; ++i)
            #pragma unroll
            for (int r = 0; r < 4; ++r) {
                const int rl = 64 * wr + 16 * i + 4 * g + r;
                mbuf[rl] = m_loc[i][r]; sbuf[rl] = s_loc[i][r];
            }
    }
    __syncthreads();
    if (wc == 1 && lm == 0) {
        #pragma unroll
        for (int i = 0; i < 4; ++i)
            #pragma unroll
            for (int r = 0; r < 4; ++r) {
                const int rl = 64 * wr + 16 * i + 4 * g + r;
                const float om = mbuf[rl], os = sbuf[rl];
                float m = m_loc[i][r], s = s_loc[i][r];
                const float nm = fmaxf(m, om);
                s = s * __builtin_exp2f(m - nm) + os * __builtin_exp2f(om - nm);
                pmax[(size_t)(row0 + rl) * NCHUNK + chunk] = nm;
                psum[(size_t)(row0 + rl) * NCHUNK + chunk] = s;
            }
    }
}

// ---------------------------------------------------------------------------
// Kernel 4: combine partials -> out += -sum lse.
// lse_nats = LN2*(gm + log2 s) - 0.5*LN2^2*X2   (X2 = sum q^2, q = log2e*x~)
__global__ void k_finish(const float* __restrict__ pmax,
                         const float* __restrict__ psum,
                         const float* __restrict__ xsq,
                         float* __restrict__ out) {
    const int row = blockIdx.x * 256 + threadIdx.x;
    const float4* pm4 = (const float4*)(pmax + (size_t)row * NCHUNK);
    const float4* ps4 = (const float4*)(psum + (size_t)row * NCHUNK);
    float pm[NCHUNK], ps[NCHUNK];
    #pragma unroll
    for (int c = 0; c < NCHUNK / 4; ++c) {
        const float4 a = pm4[c], b = ps4[c];
        pm[4*c] = a.x; pm[4*c+1] = a.y; pm[4*c+2] = a.z; pm[4*c+3] = a.w;
        ps[4*c] = b.x; ps[4*c+1] = b.y; ps[4*c+2] = b.z; ps[4*c+3] = b.w;
    }
    float gm = -__builtin_inff();
    #pragma unroll
    for (int c = 0; c < NCHUNK; ++c) gm = fmaxf(gm, pm[c]);
    float s = 0.f;
    #pragma unroll
    for (int c = 0; c < NCHUNK; ++c) s += ps[c] * __builtin_exp2f(pm[c] - gm);
    float lse = LN2 * (gm + __builtin_log2f(s)) - 0.5f * (LN2 * LN2) * xsq[row];
    #pragma unroll
    for (int m = 1; m < 64; m <<= 1) lse += __shfl_xor(lse, m);
    __shared__ float ws4[4];
    if ((threadIdx.x & 63) == 0) ws4[threadIdx.x >> 6] = lse;
    __syncthreads();
    if (threadIdx.x == 0) atomicAdd(out, -(ws4[0] + ws4[1] + ws4[2] + ws4[3]));
}

// ---------------------------------------------------------------------------
extern "C" void kernel_launch(void* const* d_in, const int* in_sizes, int n_in,
                              void* d_out, int out_size, void* d_ws, size_t ws_size,
                              hipStream_t stream) {
    const float* x  = (const float*)d_in[0];   // (8192, 512)
    const float* mu = (const float*)d_in[1];   // (8192, 512)
    const float* W  = (const float*)d_in[2];   // (512, 512)
    const float* b  = (const float*)d_in[3];   // (512,)

    char* ws = (char*)d_ws;
    unsigned char*  xb8 = (unsigned char*)(ws);                     // 4 MB
    unsigned char*  fb8 = (unsigned char*)(ws + (4u << 20));        // 4 MB
    unsigned short* mub = (unsigned short*)(ws + (8u << 20));       // 8 MB
    unsigned short* Wb  = (unsigned short*)(ws + (16u << 20));      // 512 KB
    float* xsq  = (float*)(ws + (17u << 20));                       // 32 KB
    float* fsq  = xsq + NROWS;                                      // 32 KB
    float* pmax = fsq + MROWS;                                      // 256 KB
    float* psum = pmax + (size_t)NROWS * NCHUNK;                    // 256 KB

    float* out = (float*)d_out;

    hipLaunchKernelGGL(k_convmw, dim3(MUBLK + WBLK), dim3(256), 0, stream,
                       mu, W, mub, Wb, fsq, out);
    hipLaunchKernelGGL(k_fgemm_xprep, dim3(FGB + XBLK), dim3(256), 0, stream,
                       mub, Wb, b, x, fb8, xb8, fsq, xsq);
    hipLaunchKernelGGL(k_cross, dim3(NRB, NCHUNK), dim3(256), 0, stream,
                       xb8, fb8, fsq, pmax, psum);
    hipLaunchKernelGGL(k_finish, dim3(NROWS / 256), dim3(256), 0, stream,
                       pmax, psum, xsq, out);
}